// Round 3
// baseline (201.003 us; speedup 1.0000x reference)
//
#include <hip/hip_runtime.h>
#include <math.h>

// Problem constants: src (N,C,D,H,W) = (2,1,160,192,160) fp32
#define N_ 2
#define D_ 160
#define H_ 192
#define W_ 160
#define HW_ (H_*W_)               // 30,720
#define DHW_ (D_*H_*W_)           // 4,915,200
#define TOTAL_ (N_*DHW_)          // 9,830,400
#define VPT_ 4                    // outputs per thread (along w; W_%4==0)
#define BLK_ 256
#define ELEMS_PER_BLK_ (BLK_*VPT_)        // 1024
#define BLOCKS_PER_N_ (DHW_/ELEMS_PER_BLK_) // 4800
#define NWG_ (TOTAL_/ELEMS_PER_BLK_)        // 9600 (divisible by 8)
#define NXCD_ 8

__device__ __forceinline__ void matmul3(const float A[3][3], const float B[3][3], float C[3][3]) {
    #pragma unroll
    for (int i = 0; i < 3; ++i)
        #pragma unroll
        for (int j = 0; j < 3; ++j)
            C[i][j] = A[i][0]*B[0][j] + A[i][1]*B[1][j] + A[i][2]*B[2][j];
}

// Builds mat (N,3,4) into the tail of d_out (tuple output #2).
__global__ void build_mat_kernel(const float* __restrict__ affine,
                                 const float* __restrict__ scale,
                                 const float* __restrict__ translate,
                                 const float* __restrict__ shear,
                                 float* __restrict__ mat_out) {
    int n = threadIdx.x;
    if (n >= N_) return;
    float tx = affine[n*3+0], ty = affine[n*3+1], tz = affine[n*3+2];
    float sx = scale[n*3+0],  sy = scale[n*3+1],  sz = scale[n*3+2];
    float t_xy = tanf(shear[n*6+0]), t_xz = tanf(shear[n*6+1]);
    float t_yx = tanf(shear[n*6+2]), t_yz = tanf(shear[n*6+3]);
    float t_zx = tanf(shear[n*6+4]), t_zy = tanf(shear[n*6+5]);
    float cx = cosf(tx), sxv = sinf(tx);
    float cy = cosf(ty), syv = sinf(ty);
    float cz = cosf(tz), szv = sinf(tz);
    float RX[3][3] = {{1,0,0},{0,cx,sxv},{0,-sxv,cx}};
    float RY[3][3] = {{cy,0,-syv},{0,1,0},{syv,0,cy}};
    float RZ[3][3] = {{cz,szv,0},{-szv,cz,0},{0,0,1}};
    float SC[3][3] = {{sx,0,0},{0,sy,0},{0,0,sz}};
    float SH[3][3] = {{1,t_yx,t_zx},{t_xy,1,t_zy},{t_xz,t_yz,1}};
    float M1[3][3], M2[3][3], M3[3][3], M4[3][3];
    matmul3(RY, RX, M1);
    matmul3(RZ, M1, M2);
    matmul3(SC, M2, M3);
    matmul3(SH, M3, M4);
    #pragma unroll
    for (int i = 0; i < 3; ++i) {
        #pragma unroll
        for (int j = 0; j < 3; ++j)
            mat_out[n*12 + i*4 + j] = M4[i][j];
        mat_out[n*12 + i*4 + 3] = translate[n*3 + i];
    }
}

__global__ __launch_bounds__(256)
void affine_sample_kernel(const float* __restrict__ src,
                          const float* __restrict__ mat,   // tail of d_out
                          float* __restrict__ out) {
    // XCD-chunked swizzle (R1: FETCH 85->19MB, keep).
    int bid = blockIdx.x;
    int swz = (bid & (NXCD_-1)) * (NWG_/NXCD_) + (bid >> 3);

    int n  = swz / BLOCKS_PER_N_;                       // wave-uniform
    int lb = (swz % BLOCKS_PER_N_) * ELEMS_PER_BLK_ + threadIdx.x * VPT_;

    // lb is a multiple of 4 and W_%4==0 -> all 4 outputs share one (h,d) row.
    int w0 = lb % W_;
    int t  = lb / W_;
    int h  = t % H_;
    int d  = t / H_;

    const float* m = mat + n * 12;
    float y = -1.0f + h * (2.0f / (H_ - 1));
    float z = -1.0f + d * (2.0f / (D_ - 1));
    float byx = m[1]*y + m[2]*z  + m[3];   // gx = m0*x + byx
    float byy = m[5]*y + m[6]*z  + m[7];
    float byz = m[9]*y + m[10]*z + m[11];

    int   x0[VPT_], y0[VPT_], z0[VPT_], off[VPT_];
    float wx[VPT_], wy[VPT_], wz[VPT_];
    bool  allin = true;
    #pragma unroll
    for (int k = 0; k < VPT_; ++k) {
        float x  = -1.0f + (w0 + k) * (2.0f / (W_ - 1));
        float ix = (m[0]*x + byx + 1.0f) * 0.5f * (W_ - 1);
        float iy = (m[4]*x + byy + 1.0f) * 0.5f * (H_ - 1);
        float iz = (m[8]*x + byz + 1.0f) * 0.5f * (D_ - 1);
        float fx = floorf(ix), fy = floorf(iy), fz = floorf(iz);
        wx[k] = ix - fx; wy[k] = iy - fy; wz[k] = iz - fz;
        x0[k] = (int)fx; y0[k] = (int)fy; z0[k] = (int)fz;
        off[k] = (z0[k] * H_ + y0[k]) * W_ + x0[k];
        allin &= ((unsigned)x0[k] < (unsigned)(W_-1)) &
                 ((unsigned)y0[k] < (unsigned)(H_-1)) &
                 ((unsigned)z0[k] < (unsigned)(D_-1));
    }

    const float* s = src + n * DHW_;
    float res[VPT_];

    if (__all(allin)) {
        // 32 independent gathers issued before any use -> one vmcnt drain.
        float v000[VPT_], v001[VPT_], v010[VPT_], v011[VPT_];
        float v100[VPT_], v101[VPT_], v110[VPT_], v111[VPT_];
        #pragma unroll
        for (int k = 0; k < VPT_; ++k) {
            const float* p = s + off[k];
            v000[k] = p[0];        v001[k] = p[1];
            v010[k] = p[W_];       v011[k] = p[W_ + 1];
            v100[k] = p[HW_];      v101[k] = p[HW_ + 1];
            v110[k] = p[HW_ + W_]; v111[k] = p[HW_ + W_ + 1];
        }
        #pragma unroll
        for (int k = 0; k < VPT_; ++k) {
            float c00 = v000[k] + wx[k] * (v001[k] - v000[k]);
            float c01 = v010[k] + wx[k] * (v011[k] - v010[k]);
            float c10 = v100[k] + wx[k] * (v101[k] - v100[k]);
            float c11 = v110[k] + wx[k] * (v111[k] - v110[k]);
            float c0  = c00 + wy[k] * (c01 - c00);
            float c1  = c10 + wy[k] * (c11 - c10);
            res[k] = c0 + wz[k] * (c1 - c0);
        }
    } else {
        // Boundary: clamp + zero-pad, exactly like the reference.
        #pragma unroll
        for (int k = 0; k < VPT_; ++k) {
            float acc = 0.0f;
            #pragma unroll
            for (int dz = 0; dz < 2; ++dz) {
                int  zi  = z0[k] + dz;
                bool vz  = (zi >= 0) & (zi < D_);
                int  zc  = min(max(zi, 0), D_ - 1);
                float wzz = dz ? wz[k] : 1.0f - wz[k];
                #pragma unroll
                for (int dy = 0; dy < 2; ++dy) {
                    int  yi  = y0[k] + dy;
                    bool vzy = vz & (yi >= 0) & (yi < H_);
                    int  yc  = min(max(yi, 0), H_ - 1);
                    float wzy = wzz * (dy ? wy[k] : 1.0f - wy[k]);
                    int rowoff = (zc * H_ + yc) * W_;
                    #pragma unroll
                    for (int dx = 0; dx < 2; ++dx) {
                        int  xi = x0[k] + dx;
                        bool v  = vzy & (xi >= 0) & (xi < W_);
                        int  xc = min(max(xi, 0), W_ - 1);
                        float ww = wzy * (dx ? wx[k] : 1.0f - wx[k]);
                        float val = v ? s[rowoff + xc] : 0.0f;
                        acc += ww * val;
                    }
                }
            }
            res[k] = acc;
        }
    }

    float4 o = make_float4(res[0], res[1], res[2], res[3]);
    *reinterpret_cast<float4*>(out + n * DHW_ + lb) = o;
}

extern "C" void kernel_launch(void* const* d_in, const int* in_sizes, int n_in,
                              void* d_out, int out_size, void* d_ws, size_t ws_size,
                              hipStream_t stream) {
    const float* src       = (const float*)d_in[0];
    const float* affine    = (const float*)d_in[1];
    const float* scale     = (const float*)d_in[2];
    const float* translate = (const float*)d_in[3];
    const float* shear     = (const float*)d_in[4];

    float* out     = (float*)d_out;
    float* mat_out = out + TOTAL_;   // tuple output #2: (N,3,4) flat

    build_mat_kernel<<<1, 64, 0, stream>>>(affine, scale, translate, shear, mat_out);
    affine_sample_kernel<<<NWG_, BLK_, 0, stream>>>(src, mat_out, out);
}

// Round 5
// 159.171 us; speedup vs baseline: 1.2628x; 1.2628x over previous
//
#include <hip/hip_runtime.h>
#include <math.h>

// Problem constants: src (N,C,D,H,W) = (2,1,160,192,160) fp32
#define N_ 2
#define D_ 160
#define H_ 192
#define W_ 160
#define HW_ (H_*W_)                 // 30,720
#define DHW_ (D_*H_*W_)             // 4,915,200
#define TOTAL_ (N_*DHW_)            // 9,830,400
#define BLK_ 256
#define BLOCKS_PER_SLAB_ (HW_/BLK_) // 120 blocks cover one (d,d+1) slice pair
#define PAIRS_ (D_/2)               // 80
#define BLOCKS_PER_N_ (PAIRS_*BLOCKS_PER_SLAB_) // 9600
#define NWG_ (N_*BLOCKS_PER_N_)     // 19200 (divisible by 8)
#define NXCD_ 8

__device__ __forceinline__ void matmul3(const float A[3][3], const float B[3][3], float C[3][3]) {
    #pragma unroll
    for (int i = 0; i < 3; ++i)
        #pragma unroll
        for (int j = 0; j < 3; ++j)
            C[i][j] = A[i][0]*B[0][j] + A[i][1]*B[1][j] + A[i][2]*B[2][j];
}

// Replicates the torch/jax column-stacked matrix chain. Pure function of the
// 15 scalars -> bitwise identical across all blocks that call it.
__device__ __forceinline__ void compute_mat(int n,
        const float* __restrict__ affine, const float* __restrict__ scale,
        const float* __restrict__ translate, const float* __restrict__ shear,
        float M[12]) {
    float tx = affine[n*3+0], ty = affine[n*3+1], tz = affine[n*3+2];
    float sx = scale[n*3+0],  sy = scale[n*3+1],  sz = scale[n*3+2];
    float t_xy = tanf(shear[n*6+0]), t_xz = tanf(shear[n*6+1]);
    float t_yx = tanf(shear[n*6+2]), t_yz = tanf(shear[n*6+3]);
    float t_zx = tanf(shear[n*6+4]), t_zy = tanf(shear[n*6+5]);
    float cx = cosf(tx), sxv = sinf(tx);
    float cy = cosf(ty), syv = sinf(ty);
    float cz = cosf(tz), szv = sinf(tz);
    float RX[3][3] = {{1,0,0},{0,cx,sxv},{0,-sxv,cx}};
    float RY[3][3] = {{cy,0,-syv},{0,1,0},{syv,0,cy}};
    float RZ[3][3] = {{cz,szv,0},{-szv,cz,0},{0,0,1}};
    float SC[3][3] = {{sx,0,0},{0,sy,0},{0,0,sz}};
    float SH[3][3] = {{1,t_yx,t_zx},{t_xy,1,t_zy},{t_xz,t_yz,1}};
    float M1[3][3], M2[3][3], M3[3][3], M4[3][3];
    matmul3(RY, RX, M1);
    matmul3(RZ, M1, M2);
    matmul3(SC, M2, M3);
    matmul3(SH, M3, M4);
    #pragma unroll
    for (int i = 0; i < 3; ++i) {
        #pragma unroll
        for (int j = 0; j < 3; ++j)
            M[i*4+j] = M4[i][j];
        M[i*4+3] = translate[n*3+i];
    }
}

__global__ __launch_bounds__(256)
void affine_sample_kernel(const float* __restrict__ src,
                          const float* __restrict__ affine,
                          const float* __restrict__ scale,
                          const float* __restrict__ translate,
                          const float* __restrict__ shear,
                          float* __restrict__ out,
                          float* __restrict__ mat_out) {
    // XCD-chunked swizzle (R1: FETCH 85->19MB). 19200 % 8 == 0 -> bijective.
    int bid = blockIdx.x;
    int swz = (bid & (NXCD_-1)) * (NWG_/NXCD_) + (bid >> 3);

    int n = swz / BLOCKS_PER_N_;            // wave-uniform
    int r = swz % BLOCKS_PER_N_;

    // Per-block mat: thread 0 computes this block's n into LDS (fused, no
    // second kernel). Block 0 additionally emits the (N,3,4) tuple output.
    __shared__ float sm[12];
    if (threadIdx.x == 0) {
        float M[12];
        compute_mat(n, affine, scale, translate, shear, M);
        #pragma unroll
        for (int i = 0; i < 12; ++i) sm[i] = M[i];
        if (bid == 0) {                     // bid 0 -> swz 0 -> n == 0
            #pragma unroll
            for (int i = 0; i < 12; ++i) mat_out[i] = M[i];
        }
    }
    if (bid == 0 && threadIdx.x == 1) {
        float M[12];
        compute_mat(1, affine, scale, translate, shear, M);
        #pragma unroll
        for (int i = 0; i < 12; ++i) mat_out[12 + i] = M[i];
    }
    __syncthreads();

    // VPT=2 along d: lanes stay stride-1 in w (full coalescing), second
    // output's coords are first's + a wave-uniform delta, z-slices shared in L1.
    int d0  = 2 * (r / BLOCKS_PER_SLAB_);
    int idx = (r % BLOCKS_PER_SLAB_) * BLK_ + threadIdx.x;   // [0, HW_)
    int w = idx % W_;
    int h = idx / W_;

    float x = -1.0f + w  * (2.0f / (W_ - 1));
    float y = -1.0f + h  * (2.0f / (H_ - 1));
    float z = -1.0f + d0 * (2.0f / (D_ - 1));

    float gx = sm[0]*x + sm[1]*y + sm[2]*z  + sm[3];
    float gy = sm[4]*x + sm[5]*y + sm[6]*z  + sm[7];
    float gz = sm[8]*x + sm[9]*y + sm[10]*z + sm[11];

    float ix[2], iy[2], iz[2];
    ix[0] = (gx + 1.0f) * (0.5f * (W_ - 1));
    iy[0] = (gy + 1.0f) * (0.5f * (H_ - 1));
    iz[0] = (gz + 1.0f) * (0.5f * (D_ - 1));
    const float zs = 2.0f / (D_ - 1);
    ix[1] = ix[0] + sm[2]  * zs * (0.5f * (W_ - 1));
    iy[1] = iy[0] + sm[6]  * zs * (0.5f * (H_ - 1));
    iz[1] = iz[0] + sm[10] * zs * (0.5f * (D_ - 1));

    // Branch-free: clamp + per-axis masks (valid = vx*vy*vz is separable, so
    // masking values by mx, c00*=my, c0*=mz reproduces sum(w*valid*g) exactly).
    float wxa[2], wya[2], wza[2];
    float mx0[2], mx1[2], my0[2], my1[2], mz0[2], mz1[2];
    int   r00[2], r01[2], r10[2], r11[2], xa0[2], xa1[2];
    #pragma unroll
    for (int k = 0; k < 2; ++k) {
        float fx = floorf(ix[k]), fy = floorf(iy[k]), fz = floorf(iz[k]);
        wxa[k] = ix[k] - fx; wya[k] = iy[k] - fy; wza[k] = iz[k] - fz;
        int x0 = (int)fx, y0 = (int)fy, z0 = (int)fz;
        int x1 = x0 + 1,  y1 = y0 + 1,  z1 = z0 + 1;
        mx0[k] = ((unsigned)x0 < (unsigned)W_) ? 1.0f : 0.0f;
        mx1[k] = ((unsigned)x1 < (unsigned)W_) ? 1.0f : 0.0f;
        my0[k] = ((unsigned)y0 < (unsigned)H_) ? 1.0f : 0.0f;
        my1[k] = ((unsigned)y1 < (unsigned)H_) ? 1.0f : 0.0f;
        mz0[k] = ((unsigned)z0 < (unsigned)D_) ? 1.0f : 0.0f;
        mz1[k] = ((unsigned)z1 < (unsigned)D_) ? 1.0f : 0.0f;
        int xc0 = min(max(x0, 0), W_-1), xc1 = min(max(x1, 0), W_-1);
        int yc0 = min(max(y0, 0), H_-1), yc1 = min(max(y1, 0), H_-1);
        int zc0 = min(max(z0, 0), D_-1), zc1 = min(max(z1, 0), D_-1);
        r00[k] = (zc0 * H_ + yc0) * W_;
        r01[k] = (zc0 * H_ + yc1) * W_;
        r10[k] = (zc1 * H_ + yc0) * W_;
        r11[k] = (zc1 * H_ + yc1) * W_;
        xa0[k] = xc0; xa1[k] = xc1;
    }

    const float* s = src + n * DHW_;
    // 16 independent gathers, all addresses ready -> one vmcnt drain.
    float v000[2], v001[2], v010[2], v011[2], v100[2], v101[2], v110[2], v111[2];
    #pragma unroll
    for (int k = 0; k < 2; ++k) {
        v000[k] = s[r00[k] + xa0[k]]; v001[k] = s[r00[k] + xa1[k]];
        v010[k] = s[r01[k] + xa0[k]]; v011[k] = s[r01[k] + xa1[k]];
        v100[k] = s[r10[k] + xa0[k]]; v101[k] = s[r10[k] + xa1[k]];
        v110[k] = s[r11[k] + xa0[k]]; v111[k] = s[r11[k] + xa1[k]];
    }

    float res[2];
    #pragma unroll
    for (int k = 0; k < 2; ++k) {
        float a, b, c00, c01, c10, c11, c0, c1;
        a = v000[k]*mx0[k]; b = v001[k]*mx1[k]; c00 = a + wxa[k]*(b - a);
        a = v010[k]*mx0[k]; b = v011[k]*mx1[k]; c01 = a + wxa[k]*(b - a);
        a = v100[k]*mx0[k]; b = v101[k]*mx1[k]; c10 = a + wxa[k]*(b - a);
        a = v110[k]*mx0[k]; b = v111[k]*mx1[k]; c11 = a + wxa[k]*(b - a);
        c00 *= my0[k]; c01 *= my1[k];
        c10 *= my0[k]; c11 *= my1[k];
        c0 = c00 + wya[k]*(c01 - c00);
        c1 = c10 + wya[k]*(c11 - c10);
        c0 *= mz0[k]; c1 *= mz1[k];
        res[k] = c0 + wza[k]*(c1 - c0);
    }

    int obase = n * DHW_ + d0 * HW_ + idx;
    out[obase]       = res[0];
    out[obase + HW_] = res[1];
}

extern "C" void kernel_launch(void* const* d_in, const int* in_sizes, int n_in,
                              void* d_out, int out_size, void* d_ws, size_t ws_size,
                              hipStream_t stream) {
    const float* src       = (const float*)d_in[0];
    const float* affine    = (const float*)d_in[1];
    const float* scale     = (const float*)d_in[2];
    const float* translate = (const float*)d_in[3];
    const float* shear     = (const float*)d_in[4];

    float* out     = (float*)d_out;
    float* mat_out = out + TOTAL_;   // tuple output #2: (N,3,4) flat

    affine_sample_kernel<<<NWG_, BLK_, 0, stream>>>(src, affine, scale, translate,
                                                    shear, out, mat_out);
}

// Round 9
// 145.328 us; speedup vs baseline: 1.3831x; 1.0953x over previous
//
#include <hip/hip_runtime.h>
#include <math.h>

// Problem constants: src (N,C,D,H,W) = (2,1,160,192,160) fp32
#define N_ 2
#define D_ 160
#define H_ 192
#define W_ 160
#define HW_ (H_*W_)              // 30,720
#define DHW_ (D_*H_*W_)          // 4,915,200
#define TOTAL_ (N_*DHW_)         // 9,830,400
#define BLOCKS_PER_N_ (DHW_/256) // 19,200
#define NWG_ (TOTAL_/256)        // 38,400 (divisible by 8)
#define NXCD_ 8

// 8-byte vector with 4-byte alignment: covers (x0, x0+1) with one
// global_load_dwordx2 (gfx9+ unaligned global access; if the backend
// declines it splits into 2 dwords = previous behavior, no regression).
typedef float f2a __attribute__((ext_vector_type(2), aligned(4)));

__device__ __forceinline__ void matmul3(const float A[3][3], const float B[3][3], float C[3][3]) {
    #pragma unroll
    for (int i = 0; i < 3; ++i)
        #pragma unroll
        for (int j = 0; j < 3; ++j)
            C[i][j] = A[i][0]*B[0][j] + A[i][1]*B[1][j] + A[i][2]*B[2][j];
}

// Builds mat (N,3,4) into the tail of d_out (tuple output #2). Separate
// kernel: keeps the tanf/sincos chain out of the 19k-block hot kernel
// (R3 post-mortem: fused trig + barrier cost ~10 us).
__global__ void build_mat_kernel(const float* __restrict__ affine,
                                 const float* __restrict__ scale,
                                 const float* __restrict__ translate,
                                 const float* __restrict__ shear,
                                 float* __restrict__ mat_out) {
    int n = threadIdx.x;
    if (n >= N_) return;
    float tx = affine[n*3+0], ty = affine[n*3+1], tz = affine[n*3+2];
    float sx = scale[n*3+0],  sy = scale[n*3+1],  sz = scale[n*3+2];
    float t_xy = tanf(shear[n*6+0]), t_xz = tanf(shear[n*6+1]);
    float t_yx = tanf(shear[n*6+2]), t_yz = tanf(shear[n*6+3]);
    float t_zx = tanf(shear[n*6+4]), t_zy = tanf(shear[n*6+5]);
    float cx = cosf(tx), sxv = sinf(tx);
    float cy = cosf(ty), syv = sinf(ty);
    float cz = cosf(tz), szv = sinf(tz);
    float RX[3][3] = {{1,0,0},{0,cx,sxv},{0,-sxv,cx}};
    float RY[3][3] = {{cy,0,-syv},{0,1,0},{syv,0,cy}};
    float RZ[3][3] = {{cz,szv,0},{-szv,cz,0},{0,0,1}};
    float SC[3][3] = {{sx,0,0},{0,sy,0},{0,0,sz}};
    float SH[3][3] = {{1,t_yx,t_zx},{t_xy,1,t_zy},{t_xz,t_yz,1}};
    float M1[3][3], M2[3][3], M3[3][3], M4[3][3];
    matmul3(RY, RX, M1);
    matmul3(RZ, M1, M2);
    matmul3(SC, M2, M3);
    matmul3(SH, M3, M4);
    #pragma unroll
    for (int i = 0; i < 3; ++i) {
        #pragma unroll
        for (int j = 0; j < 3; ++j)
            mat_out[n*12 + i*4 + j] = M4[i][j];
        mat_out[n*12 + i*4 + 3] = translate[n*3 + i];
    }
}

__global__ __launch_bounds__(256)
void affine_sample_kernel(const float* __restrict__ src,
                          const float* __restrict__ mat,   // tail of d_out
                          float* __restrict__ out) {
    // XCD-chunked swizzle (R1: FETCH 85->19MB; keep). 38400 % 8 == 0.
    int bid = blockIdx.x;
    int swz = (bid & (NXCD_-1)) * (NWG_/NXCD_) + (bid >> 3);

    int n     = swz / BLOCKS_PER_N_;            // wave-uniform
    int local = (swz % BLOCKS_PER_N_) * 256 + threadIdx.x;

    int w = local % W_;
    int t = local / W_;
    int h = t % H_;
    int d = t / H_;

    const float* m = mat + n * 12;

    float x = -1.0f + w * (2.0f / (W_ - 1));
    float y = -1.0f + h * (2.0f / (H_ - 1));
    float z = -1.0f + d * (2.0f / (D_ - 1));

    float gx = m[0]*x + m[1]*y + m[2]*z  + m[3];
    float gy = m[4]*x + m[5]*y + m[6]*z  + m[7];
    float gz = m[8]*x + m[9]*y + m[10]*z + m[11];

    float ix = (gx + 1.0f) * (0.5f * (W_ - 1));
    float iy = (gy + 1.0f) * (0.5f * (H_ - 1));
    float iz = (gz + 1.0f) * (0.5f * (D_ - 1));

    float fx = floorf(ix), fy = floorf(iy), fz = floorf(iz);
    float wx = ix - fx, wy = iy - fy, wz = iz - fz;
    int x0 = (int)fx, y0 = (int)fy, z0 = (int)fz;

    const float* s = src + n * DHW_;
    float acc;

    bool interior = ((unsigned)x0 < (unsigned)(W_-1)) &
                    ((unsigned)y0 < (unsigned)(H_-1)) &
                    ((unsigned)z0 < (unsigned)(D_-1));

    if (__all(interior)) {
        // 4 pair-loads instead of 8 scalar gathers: halves VMEM instruction
        // count (TA address-processing) at identical byte traffic. Two
        // 64-bit bases (p, p+HW_); the +W_ variants fold into offset:640.
        const float* p = s + (z0 * H_ + y0) * W_ + x0;
        f2a a00 = *(const f2a*)(p);             // v000 v001
        f2a a01 = *(const f2a*)(p + W_);        // v010 v011
        f2a a10 = *(const f2a*)(p + HW_);       // v100 v101
        f2a a11 = *(const f2a*)(p + HW_ + W_);  // v110 v111
        float c00 = a00.x + wx * (a00.y - a00.x);
        float c01 = a01.x + wx * (a01.y - a01.x);
        float c10 = a10.x + wx * (a10.y - a10.x);
        float c11 = a11.x + wx * (a11.y - a11.x);
        float c0  = c00 + wy * (c01 - c00);
        float c1  = c10 + wy * (c11 - c10);
        acc = c0 + wz * (c1 - c0);
    } else {
        // Boundary path: clamp + zero-pad, exactly like the reference.
        acc = 0.0f;
        #pragma unroll
        for (int dz = 0; dz < 2; ++dz) {
            int  zi  = z0 + dz;
            bool vz  = (zi >= 0) & (zi < D_);
            int  zc  = min(max(zi, 0), D_ - 1);
            float wzz = dz ? wz : 1.0f - wz;
            #pragma unroll
            for (int dy = 0; dy < 2; ++dy) {
                int  yi  = y0 + dy;
                bool vzy = vz & (yi >= 0) & (yi < H_);
                int  yc  = min(max(yi, 0), H_ - 1);
                float wzy = wzz * (dy ? wy : 1.0f - wy);
                int rowoff = (zc * H_ + yc) * W_;
                #pragma unroll
                for (int dx = 0; dx < 2; ++dx) {
                    int  xi = x0 + dx;
                    bool v  = vzy & (xi >= 0) & (xi < W_);
                    int  xc = min(max(xi, 0), W_ - 1);
                    float ww = wzy * (dx ? wx : 1.0f - wx);
                    float val = v ? s[rowoff + xc] : 0.0f;
                    acc += ww * val;
                }
            }
        }
    }
    out[n * DHW_ + local] = acc;
}

extern "C" void kernel_launch(void* const* d_in, const int* in_sizes, int n_in,
                              void* d_out, int out_size, void* d_ws, size_t ws_size,
                              hipStream_t stream) {
    const float* src       = (const float*)d_in[0];
    const float* affine    = (const float*)d_in[1];
    const float* scale     = (const float*)d_in[2];
    const float* translate = (const float*)d_in[3];
    const float* shear     = (const float*)d_in[4];

    float* out     = (float*)d_out;
    float* mat_out = out + TOTAL_;   // tuple output #2: (N,3,4) flat

    build_mat_kernel<<<1, 64, 0, stream>>>(affine, scale, translate, shear, mat_out);
    affine_sample_kernel<<<NWG_, 256, 0, stream>>>(src, mat_out, out);
}